// Round 1
// baseline (471.611 us; speedup 1.0000x reference)
//
#include <hip/hip_runtime.h>

typedef _Float16 h8  __attribute__((ext_vector_type(8)));
typedef _Float16 h4v __attribute__((ext_vector_type(4)));
typedef float    f32x4 __attribute__((ext_vector_type(4)));

#define QSTR 264   // rA row stride in halfs (256 + 8 pad; 528 B = 33*16, b128-aligned)

// Block: 256 threads = 4 waves. Tile: (b, k, 64 q) x full 256 a.
// Stage 1: T[64q x 256e] = q_tile @ w[k]      (fp16 MFMA, fp32 acc)
// Stage 2: out[64q x 256a] = T @ da[b]^T      (fp16 MFMA, fp32 acc)
// Epilogue: + vq[q] + vd[a] + b_k, sigmoid, store fp32.
__global__ __launch_bounds__(256, 3)
void ntn_fused(const float* __restrict__ qg, const float* __restrict__ dg,
               const float* __restrict__ wg, const float* __restrict__ Vg,
               const float* __restrict__ bg, float* __restrict__ og)
{
    // rA: q tile (fp16, 64 x QSTR), later reused for T (same layout).
    // rB: stage1 w^T chunk (swizzled, 256e x 32d, stride 32) / stage2 da chunk
    //     (256a x 40, pad-8) / small float scratch for vq partials + vq/vd stash.
    __shared__ __align__(16) _Float16 rA[64 * QSTR];   // 33792 B
    __shared__ __align__(16) _Float16 rB[256 * 40];    // 20480 B  (total 54272 B -> 3 blocks/CU)

    const int tid  = threadIdx.x;
    const int wv   = tid >> 6;       // wave 0..3
    const int lane = tid & 63;
    const int quad = lane >> 4;      // k-group for A/B frags, row-group for C
    const int l15  = lane & 15;

    const int bid = blockIdx.x;
    const int qt = bid & 3, kk = (bid >> 2) & 15, bb = bid >> 6;

    const float* wk = wg + kk * 65536;                  // w[k]  (256d x 256e)
    const float* qb = qg + (bb * 256 + qt * 64) * 256;  // q rows q0..q0+63
    const float* db = dg + bb * 65536;                  // da[b] (256a x 256d)
    const float* Vq = Vg + kk * 512;
    const float* Vd = Vq + 256;
    const float  bk = bg[kk];

    // ---- load q tile 64x256 fp32 -> fp16 into rA (coalesced float4, half4 LDS writes)
    for (int r = 0; r < 16; ++r) {
        int f  = r * 256 + tid;        // float4 index over 64 rows x 64 f4/row
        int qq = f >> 6;
        int d4 = (f & 63) << 2;
        f32x4 v = *(const f32x4*)&qb[qq * 256 + d4];
        h4v h;
        h[0] = (_Float16)v[0]; h[1] = (_Float16)v[1];
        h[2] = (_Float16)v[2]; h[3] = (_Float16)v[3];
        *(h4v*)&rA[qq * QSTR + d4] = h;
    }

    const f32x4 zero = {0.f, 0.f, 0.f, 0.f};
    f32x4 acc[4][4];
    #pragma unroll
    for (int mt = 0; mt < 4; ++mt)
        #pragma unroll
        for (int nt = 0; nt < 4; ++nt) acc[mt][nt] = zero;

    const int e0  = (tid & 63) << 2;   // e-group base (4 e's per thread)
    const int d0g = tid >> 6;          // d-group 0..3 (8 d's per group)

    // ================== STAGE 1: T = q @ w[k], K-chunks of 32 d ==================
    for (int dc = 0; dc < 8; ++dc) {
        // stage w^T chunk: read 8 full rows per wave coalesced (1 KB/instr),
        // transpose in regs, write b128 runs along d into swizzled rB.
        f32x4 Ld[8];
        #pragma unroll
        for (int r = 0; r < 8; ++r)
            Ld[r] = *(const f32x4*)&wk[(dc * 32 + d0g * 8 + r) * 256 + e0];
        #pragma unroll
        for (int i = 0; i < 4; ++i) {
            h8 hv;
            #pragma unroll
            for (int r = 0; r < 8; ++r) hv[r] = (_Float16)Ld[r][i];
            int e   = e0 + i;
            int grp = d0g ^ ((e >> 2) & 3);          // XOR swizzle, 16B groups
            *(h8*)&rB[e * 32 + (grp << 3)] = hv;
        }
        __syncthreads();

        h8 af[4], bf[4];
        #pragma unroll
        for (int mt = 0; mt < 4; ++mt)
            af[mt] = *(const h8*)&rA[(mt * 16 + l15) * QSTR + dc * 32 + quad * 8];
        #pragma unroll
        for (int nt = 0; nt < 4; ++nt) {
            int n   = wv * 64 + nt * 16 + l15;       // e index
            int grp = quad ^ ((n >> 2) & 3);
            bf[nt] = *(const h8*)&rB[n * 32 + (grp << 3)];
        }
        #pragma unroll
        for (int mt = 0; mt < 4; ++mt)
            #pragma unroll
            for (int nt = 0; nt < 4; ++nt)
                acc[mt][nt] = __builtin_amdgcn_mfma_f32_16x16x32_f16(
                    af[mt], bf[nt], acc[mt][nt], 0, 0, 0);
        __syncthreads();
    }

    // ---- vq partials: thread (q=tid&63, seg=tid>>6) sums 64 d's from fp16 q tile
    {
        float vqp = 0.f;
        int qq = tid & 63, seg = tid >> 6;
        for (int j = seg * 64; j < seg * 64 + 64; j += 8) {
            h8 hv = *(const h8*)&rA[qq * QSTR + j];
            #pragma unroll
            for (int u = 0; u < 8; ++u) vqp += (float)hv[u] * Vq[j + u];
        }
        ((float*)rB)[tid] = vqp;
    }
    __syncthreads();

    // ---- write T (fp16) into rA (overwrites q), reduce vq partials
    float vq_r = 0.f;
    if (tid < 64) {
        const float* fB = (const float*)rB;
        vq_r = fB[tid] + fB[tid + 64] + fB[tid + 128] + fB[tid + 192];
    }
    #pragma unroll
    for (int mt = 0; mt < 4; ++mt)
        #pragma unroll
        for (int nt = 0; nt < 4; ++nt) {
            int e = wv * 64 + nt * 16 + l15;
            #pragma unroll
            for (int reg = 0; reg < 4; ++reg) {
                int q = mt * 16 + quad * 4 + reg;    // C/D: row = quad*4+reg, col = l15
                rA[q * QSTR + e] = (_Float16)acc[mt][nt][reg];
            }
        }
    __syncthreads();

    #pragma unroll
    for (int mt = 0; mt < 4; ++mt)
        #pragma unroll
        for (int nt = 0; nt < 4; ++nt) acc[mt][nt] = zero;

    // ================== STAGE 2: out = T @ da^T, K-chunks of 32 e =================
    float vd_r = 0.f;
    for (int ec = 0; ec < 8; ++ec) {
        // stage da chunk 256a x 32e (pad-40 rows, half4 writes)
        for (int r = 0; r < 8; ++r) {
            int f  = r * 256 + tid;
            int a  = f >> 3;
            int e4 = (f & 7) << 2;
            f32x4 v = *(const f32x4*)&db[a * 256 + ec * 32 + e4];
            h4v h;
            h[0] = (_Float16)v[0]; h[1] = (_Float16)v[1];
            h[2] = (_Float16)v[2]; h[3] = (_Float16)v[3];
            *(h4v*)&rB[a * 40 + e4] = h;
        }
        __syncthreads();

        // vd partial folded into the chunk (thread a = tid reads its own row)
        #pragma unroll
        for (int j = 0; j < 32; j += 8) {
            h8 hv = *(const h8*)&rB[tid * 40 + j];
            #pragma unroll
            for (int u = 0; u < 8; ++u) vd_r += (float)hv[u] * Vd[ec * 32 + j + u];
        }

        h8 af[4], bf[4];
        #pragma unroll
        for (int mt = 0; mt < 4; ++mt)
            af[mt] = *(const h8*)&rA[(mt * 16 + l15) * QSTR + ec * 32 + quad * 8];
        #pragma unroll
        for (int nt = 0; nt < 4; ++nt)
            bf[nt] = *(const h8*)&rB[(wv * 64 + nt * 16 + l15) * 40 + quad * 8];
        #pragma unroll
        for (int mt = 0; mt < 4; ++mt)
            #pragma unroll
            for (int nt = 0; nt < 4; ++nt)
                acc[mt][nt] = __builtin_amdgcn_mfma_f32_16x16x32_f16(
                    af[mt], bf[nt], acc[mt][nt], 0, 0, 0);
        __syncthreads();
    }

    // ---- stash vq/vd into rB scratch (fp32), then epilogue
    {
        float* fB = (float*)rB;
        if (tid < 64) fB[tid] = vq_r;
        fB[64 + tid] = vd_r;       // a = tid
    }
    __syncthreads();

    {
        const float* vql = (const float*)rB;
        const float* vdl = vql + 64;
        float* ob = og + ((bb * 16 + kk) * 256 + qt * 64) * 256;
        #pragma unroll
        for (int mt = 0; mt < 4; ++mt)
            #pragma unroll
            for (int nt = 0; nt < 4; ++nt) {
                int a = wv * 64 + nt * 16 + l15;
                float va = vdl[a];
                #pragma unroll
                for (int reg = 0; reg < 4; ++reg) {
                    int q = mt * 16 + quad * 4 + reg;
                    float x = acc[mt][nt][reg] + vql[q] + va + bk;
                    ob[q * 256 + a] = 1.0f / (1.0f + __expf(-x));
                }
            }
    }
}

extern "C" void kernel_launch(void* const* d_in, const int* in_sizes, int n_in,
                              void* d_out, int out_size, void* d_ws, size_t ws_size,
                              hipStream_t stream) {
    (void)in_sizes; (void)n_in; (void)d_ws; (void)ws_size; (void)out_size;
    const float* qg = (const float*)d_in[0];
    const float* dg = (const float*)d_in[1];
    const float* wg = (const float*)d_in[2];
    const float* Vg = (const float*)d_in[3];
    const float* bg = (const float*)d_in[4];
    float* og = (float*)d_out;
    ntn_fused<<<dim3(4096), dim3(256), 0, stream>>>(qg, dg, wg, Vg, bg, og);
}

// Round 2
// 377.356 us; speedup vs baseline: 1.2498x; 1.2498x over previous
//
#include <hip/hip_runtime.h>

typedef _Float16 h8  __attribute__((ext_vector_type(8)));
typedef _Float16 h4v __attribute__((ext_vector_type(4)));
typedef float    f32x4 __attribute__((ext_vector_type(4)));

// ---------------- workspace layout (bytes) ----------------
#define WS_W_OFF   0u            // ws[16][8][1024 slots * 16B] = 2 MB  (w^T, chunked+swizzled fp16)
#define WS_Q_OFF   (2u<<20)      // qs[64*256][256] fp16, row-swizzled           = 8 MB
#define WS_D_OFF   (10u<<20)     // das[64][8][1024 slots * 16B] chunked+swizzled = 8 MB
#define WS_VQ_OFF  (18u<<20)     // vq[64][16][256] fp32 = 4 MB
#define WS_VD_OFF  (22u<<20)     // vd[64][16][256] fp32 = 4 MB
#define WS_NEED    (26u<<20)

// ---------------- async global->LDS (16B/lane, lane-linear LDS dest) ----------------
__device__ __forceinline__ void gld16(const void* g, void* l) {
    __builtin_amdgcn_global_load_lds(
        (const __attribute__((address_space(1))) unsigned int*)g,
        (__attribute__((address_space(3))) unsigned int*)l, 16, 0, 0);
}

// ============================ PREP KERNELS ============================

// qs[row][g*8+j] = fp16( q[row][ (g ^ (row&31))*8 + j ] )   (16B-group XOR swizzle)
__global__ void prep_q(const float* __restrict__ qg, _Float16* __restrict__ qs) {
    int t0 = blockIdx.x * 256 + threadIdx.x;
    #pragma unroll
    for (int r = 0; r < 4; ++r) {
        int s   = r * 131072 + t0;         // 16B slot, 524288 total
        int row = s >> 5;                  // b*256+q
        int g   = s & 31;
        int src = row * 256 + ((g ^ (row & 31)) << 3);
        f32x4 v0 = *(const f32x4*)&qg[src];
        f32x4 v1 = *(const f32x4*)&qg[src + 4];
        h8 h;
        #pragma unroll
        for (int i = 0; i < 4; ++i) { h[i] = (_Float16)v0[i]; h[4 + i] = (_Float16)v1[i]; }
        *(h8*)&qs[s * 8] = h;
    }
}

// das chunk layout per (b,ec): slot = (a>>1)*8 + (((a&1)*4 + (e'>>3)) ^ ((a>>1)&7))
__global__ void prep_da(const float* __restrict__ dg, _Float16* __restrict__ das) {
    int t0 = blockIdx.x * 256 + threadIdx.x;
    #pragma unroll
    for (int r = 0; r < 4; ++r) {
        int s    = r * 131072 + t0;
        int cidx = s >> 10;                // b*8+ec
        int sl   = s & 1023;
        int b = cidx >> 3, ec = cidx & 7;
        int a2 = sl >> 3, g = sl & 7;
        int u  = g ^ (a2 & 7);
        int a  = a2 * 2 + (u >> 2);
        int e  = ec * 32 + (u & 3) * 8;
        const float* src = dg + b * 65536 + a * 256 + e;
        f32x4 v0 = *(const f32x4*)&src[0];
        f32x4 v1 = *(const f32x4*)&src[4];
        h8 h;
        #pragma unroll
        for (int i = 0; i < 4; ++i) { h[i] = (_Float16)v0[i]; h[4 + i] = (_Float16)v1[i]; }
        *(h8*)&das[s * 8] = h;
    }
}

// ws chunk per (k,dc): slot = (e>>1)*8 + (((e&1)*4 + (d'>>3)) ^ ((e>>1)&7)), data = w[k][dc*32+d'][e]
__global__ void prep_w(const float* __restrict__ wg, _Float16* __restrict__ wsw) {
    __shared__ float lt[32 * 256];
    int tid = threadIdx.x;
    int k = blockIdx.x >> 3, dc = blockIdx.x & 7;
    const float* src = wg + k * 65536 + dc * 32 * 256;
    #pragma unroll
    for (int r = 0; r < 8; ++r) {
        int idx = r * 256 + tid;
        int d = idx >> 6, e4 = (idx & 63) << 2;
        *(f32x4*)&lt[d * 256 + e4] = *(const f32x4*)&src[d * 256 + e4];
    }
    __syncthreads();
    #pragma unroll
    for (int r = 0; r < 4; ++r) {
        int sl = r * 256 + tid;
        int e2 = sl >> 3, g = sl & 7;
        int u  = g ^ (e2 & 7);
        int e  = e2 * 2 + (u >> 2);
        int dp = (u & 3) * 8;
        h8 h;
        #pragma unroll
        for (int j = 0; j < 8; ++j) h[j] = (_Float16)lt[(dp + j) * 256 + e];
        *(h8*)&wsw[(blockIdx.x * 1024 + sl) * 8] = h;
    }
}

// vq[b][k][q] = q[b,q,:].Vq[k]; vd[b][k][a] = da[b,a,:].Vd[k]   (fp32)
__global__ void prep_v(const float* __restrict__ qg, const float* __restrict__ dg,
                       const float* __restrict__ Vg, float* __restrict__ vq,
                       float* __restrict__ vd) {
    __shared__ float Vl[16 * 256];   // 16 KB, reused as reduce scratch
    int blk = blockIdx.x, t = threadIdx.x;
    int mode = blk >> 8;                       // 0: vq, 1: vd
    int b = (blk & 255) >> 2, qc = blk & 3;
    const float* srcb = (mode ? dg : qg) + b * 65536;
    float* outp = mode ? vd : vq;
    int voff = mode ? 256 : 0;
    #pragma unroll
    for (int r = 0; r < 4; ++r) {
        int idx = r * 256 + t;
        int k = idx >> 6, d4 = (idx & 63) << 2;
        *(f32x4*)&Vl[k * 256 + d4] = *(const f32x4*)&Vg[k * 512 + voff + d4];
    }
    __syncthreads();
    int ql = t & 63, seg = t >> 6;
    const float* row = srcb + (qc * 64 + ql) * 256 + seg * 64;
    float s[16];
    #pragma unroll
    for (int k = 0; k < 16; ++k) s[k] = 0.f;
    for (int d4 = 0; d4 < 64; d4 += 4) {
        f32x4 rv = *(const f32x4*)&row[d4];
        #pragma unroll
        for (int k = 0; k < 16; ++k) {
            f32x4 vv = *(const f32x4*)&Vl[k * 256 + seg * 64 + d4];
            s[k] += rv[0] * vv[0] + rv[1] * vv[1] + rv[2] * vv[2] + rv[3] * vv[3];
        }
    }
    __syncthreads();
    #pragma unroll
    for (int k = 0; k < 16; ++k) Vl[(seg * 16 + k) * 64 + ql] = s[k];
    __syncthreads();
    #pragma unroll
    for (int i = 0; i < 4; ++i) {
        int idx = i * 256 + t;
        int k = idx >> 6, qq = idx & 63;
        float sum = Vl[(0 * 16 + k) * 64 + qq] + Vl[(1 * 16 + k) * 64 + qq] +
                    Vl[(2 * 16 + k) * 64 + qq] + Vl[(3 * 16 + k) * 64 + qq];
        outp[(b * 16 + k) * 256 + qc * 64 + qq] = sum;
    }
}

// ============================ HOT KERNEL ============================
__global__ __launch_bounds__(256, 3)
void ntn_hot(const _Float16* __restrict__ qs, const _Float16* __restrict__ das,
             const _Float16* __restrict__ wsw, const float* __restrict__ vq,
             const float* __restrict__ vd, const float* __restrict__ bg,
             float* __restrict__ og)
{
    __shared__ __align__(16) _Float16 rA[64 * 256];   // 32 KB: swizzled q, then T
    __shared__ __align__(16) _Float16 wB[256 * 32];   // 16 KB: B-operand chunk

    const int tid  = threadIdx.x;
    const int wv   = tid >> 6;
    const int lane = tid & 63;
    const int quad = lane >> 4;
    const int l15  = lane & 15;

    const int bid = blockIdx.x;
    const int qt = bid & 3, kk = (bid >> 2) & 15, bb = bid >> 6;

    // ---- stage q tile (32 KB, pre-swizzled in global -> lane-linear copy)
    const char* qsrc = (const char*)(qs + (bb * 256 + qt * 64) * 256);
    #pragma unroll
    for (int r = 0; r < 8; ++r) {
        int base = r * 256 + wv * 64;
        gld16(qsrc + (base + lane) * 16, (char*)rA + base * 16);
    }

    const char* wsrc = (const char*)wsw + kk * 8 * 16384;
    const char* dsrc = (const char*)das + bb * 8 * 16384;

    // ---- stage w chunk 0
    #pragma unroll
    for (int r = 0; r < 4; ++r) {
        int base = r * 256 + wv * 64;
        gld16(wsrc + (base + lane) * 16, (char*)wB + base * 16);
    }
    __syncthreads();

    // frag address constants
    int rowAo[4], rswz[4];
    #pragma unroll
    for (int mt = 0; mt < 4; ++mt) {
        int row = mt * 16 + l15;
        rowAo[mt] = row * 256;
        rswz[mt]  = row & 31;
    }
    int addrB[4];
    #pragma unroll
    for (int nt = 0; nt < 4; ++nt) {
        int e = wv * 64 + nt * 16 + l15;
        addrB[nt] = (e >> 1) * 64 + (((((e & 1) << 2) + quad) ^ ((e >> 1) & 7)) << 3);
    }

    const f32x4 zero = {0.f, 0.f, 0.f, 0.f};
    f32x4 acc[4][4];
    #pragma unroll
    for (int mt = 0; mt < 4; ++mt)
        #pragma unroll
        for (int nt = 0; nt < 4; ++nt) acc[mt][nt] = zero;

    // ================= STAGE 1: T = q @ w[k] =================
    for (int dc = 0; dc < 8; ++dc) {
        h8 af[4], bf[4];
        #pragma unroll
        for (int mt = 0; mt < 4; ++mt)
            af[mt] = *(const h8*)&rA[rowAo[mt] + ((((dc << 2) + quad) ^ rswz[mt]) << 3)];
        #pragma unroll
        for (int nt = 0; nt < 4; ++nt)
            bf[nt] = *(const h8*)&wB[addrB[nt]];
        #pragma unroll
        for (int mt = 0; mt < 4; ++mt)
            #pragma unroll
            for (int nt = 0; nt < 4; ++nt)
                acc[mt][nt] = __builtin_amdgcn_mfma_f32_16x16x32_f16(
                    af[mt], bf[nt], acc[mt][nt], 0, 0, 0);
        __syncthreads();
        if (dc < 7) {
            #pragma unroll
            for (int r = 0; r < 4; ++r) {
                int base = r * 256 + wv * 64;
                gld16(wsrc + (dc + 1) * 16384 + (base + lane) * 16, (char*)wB + base * 16);
            }
            __syncthreads();
        }
    }

    // ---- transition: stage da chunk 0, write T (swizzled) into rA
    #pragma unroll
    for (int r = 0; r < 4; ++r) {
        int base = r * 256 + wv * 64;
        gld16(dsrc + (base + lane) * 16, (char*)wB + base * 16);
    }
    #pragma unroll
    for (int mt = 0; mt < 4; ++mt)
        #pragma unroll
        for (int nt = 0; nt < 4; ++nt) {
            int e = wv * 64 + nt * 16 + l15;
            #pragma unroll
            for (int reg = 0; reg < 4; ++reg) {
                int q = mt * 16 + quad * 4 + reg;
                rA[q * 256 + ((((e >> 3) ^ (q & 31)) << 3) | (e & 7))] =
                    (_Float16)acc[mt][nt][reg];
            }
        }
    #pragma unroll
    for (int mt = 0; mt < 4; ++mt)
        #pragma unroll
        for (int nt = 0; nt < 4; ++nt) acc[mt][nt] = zero;
    __syncthreads();

    // ================= STAGE 2: out = T @ da[b]^T =================
    for (int ec = 0; ec < 8; ++ec) {
        h8 af[4], bf[4];
        #pragma unroll
        for (int mt = 0; mt < 4; ++mt)
            af[mt] = *(const h8*)&rA[rowAo[mt] + ((((ec << 2) + quad) ^ rswz[mt]) << 3)];
        #pragma unroll
        for (int nt = 0; nt < 4; ++nt)
            bf[nt] = *(const h8*)&wB[addrB[nt]];
        #pragma unroll
        for (int mt = 0; mt < 4; ++mt)
            #pragma unroll
            for (int nt = 0; nt < 4; ++nt)
                acc[mt][nt] = __builtin_amdgcn_mfma_f32_16x16x32_f16(
                    af[mt], bf[nt], acc[mt][nt], 0, 0, 0);
        __syncthreads();
        if (ec < 7) {
            #pragma unroll
            for (int r = 0; r < 4; ++r) {
                int base = r * 256 + wv * 64;
                gld16(dsrc + (ec + 1) * 16384 + (base + lane) * 16, (char*)wB + base * 16);
            }
            __syncthreads();
        }
    }

    // ================= epilogue =================
    const float* vqp = vq + ((bb * 16 + kk) << 8) + qt * 64;
    const float* vdp = vd + ((bb * 16 + kk) << 8);
    const float  bk  = bg[kk];
    float vdr[4];
    #pragma unroll
    for (int nt = 0; nt < 4; ++nt) vdr[nt] = vdp[wv * 64 + nt * 16 + l15];
    float* ob = og + (((bb * 16 + kk) * 256 + qt * 64) << 8);
    #pragma unroll
    for (int mt = 0; mt < 4; ++mt) {
        float vqv[4];
        #pragma unroll
        for (int r = 0; r < 4; ++r) vqv[r] = vqp[mt * 16 + quad * 4 + r];
        #pragma unroll
        for (int nt = 0; nt < 4; ++nt)
            #pragma unroll
            for (int r = 0; r < 4; ++r) {
                float x = acc[mt][nt][r] + vqv[r] + vdr[nt] + bk;
                float y = __builtin_amdgcn_rcpf(1.0f + __expf(-x));
                __builtin_nontemporal_store(
                    y, &ob[(mt * 16 + quad * 4 + r) * 256 + wv * 64 + nt * 16 + l15]);
            }
    }
}

// ============================ FALLBACK (round-1 kernel) ============================
#define QSTR 264
__global__ __launch_bounds__(256, 3)
void ntn_fused_fb(const float* __restrict__ qg, const float* __restrict__ dg,
                  const float* __restrict__ wg, const float* __restrict__ Vg,
                  const float* __restrict__ bg, float* __restrict__ og)
{
    __shared__ __align__(16) _Float16 rA[64 * QSTR];
    __shared__ __align__(16) _Float16 rB[256 * 40];
    const int tid  = threadIdx.x;
    const int wv   = tid >> 6;
    const int lane = tid & 63;
    const int quad = lane >> 4;
    const int l15  = lane & 15;
    const int bid = blockIdx.x;
    const int qt = bid & 3, kk = (bid >> 2) & 15, bb = bid >> 6;
    const float* wk = wg + kk * 65536;
    const float* qb = qg + (bb * 256 + qt * 64) * 256;
    const float* db = dg + bb * 65536;
    const float* Vq = Vg + kk * 512;
    const float* Vd = Vq + 256;
    const float  bk = bg[kk];
    for (int r = 0; r < 16; ++r) {
        int f = r * 256 + tid;
        int qq = f >> 6, d4 = (f & 63) << 2;
        f32x4 v = *(const f32x4*)&qb[qq * 256 + d4];
        h4v h; h[0]=(_Float16)v[0]; h[1]=(_Float16)v[1]; h[2]=(_Float16)v[2]; h[3]=(_Float16)v[3];
        *(h4v*)&rA[qq * QSTR + d4] = h;
    }
    const f32x4 zero = {0.f,0.f,0.f,0.f};
    f32x4 acc[4][4];
    #pragma unroll
    for (int mt = 0; mt < 4; ++mt)
        #pragma unroll
        for (int nt = 0; nt < 4; ++nt) acc[mt][nt] = zero;
    const int e0 = (tid & 63) << 2;
    const int d0g = tid >> 6;
    for (int dc = 0; dc < 8; ++dc) {
        f32x4 Ld[8];
        #pragma unroll
        for (int r = 0; r < 8; ++r)
            Ld[r] = *(const f32x4*)&wk[(dc * 32 + d0g * 8 + r) * 256 + e0];
        #pragma unroll
        for (int i = 0; i < 4; ++i) {
            h8 hv;
            #pragma unroll
            for (int r = 0; r < 8; ++r) hv[r] = (_Float16)Ld[r][i];
            int e = e0 + i;
            int grp = d0g ^ ((e >> 2) & 3);
            *(h8*)&rB[e * 32 + (grp << 3)] = hv;
        }
        __syncthreads();
        h8 af[4], bf[4];
        #pragma unroll
        for (int mt = 0; mt < 4; ++mt)
            af[mt] = *(const h8*)&rA[(mt * 16 + l15) * QSTR + dc * 32 + quad * 8];
        #pragma unroll
        for (int nt = 0; nt < 4; ++nt) {
            int n = wv * 64 + nt * 16 + l15;
            int grp = quad ^ ((n >> 2) & 3);
            bf[nt] = *(const h8*)&rB[n * 32 + (grp << 3)];
        }
        #pragma unroll
        for (int mt = 0; mt < 4; ++mt)
            #pragma unroll
            for (int nt = 0; nt < 4; ++nt)
                acc[mt][nt] = __builtin_amdgcn_mfma_f32_16x16x32_f16(af[mt], bf[nt], acc[mt][nt], 0, 0, 0);
        __syncthreads();
    }
    {
        float vqp = 0.f;
        int qq = tid & 63, seg = tid >> 6;
        for (int j = seg * 64; j < seg * 64 + 64; j += 8) {
            h8 hv = *(const h8*)&rA[qq * QSTR + j];
            #pragma unroll
            for (int u = 0; u < 8; ++u) vqp += (float)hv[u] * Vq[j + u];
        }
        ((float*)rB)[tid] = vqp;
    }
    __syncthreads();
    float vq_r = 0.f;
    if (tid < 64) {
        const float* fB = (const float*)rB;
        vq_r = fB[tid] + fB[tid + 64] + fB[tid + 128] + fB[tid + 192];
    }
    #pragma unroll
    for (int mt = 0; mt < 4; ++mt)
        #pragma unroll
        for (int nt = 0; nt < 4; ++nt) {
            int e = wv * 64 + nt * 16 + l15;
            #pragma unroll
            for (int reg = 0; reg < 4; ++reg) {
                int q = mt * 16 + quad * 4 + reg;
                rA[q * QSTR + e] = (_Float16)acc[mt][nt][reg];
            }
        }
    __syncthreads();
    #pragma unroll
    for (int mt = 0; mt < 4; ++mt)
        #pragma unroll
        for (int nt = 0; nt < 4; ++nt) acc[mt][nt] = zero;
    float vd_r = 0.f;
    for (int ec = 0; ec < 8; ++ec) {
        for (int r = 0; r < 8; ++r) {
            int f = r * 256 + tid;
            int a = f >> 3, e4 = (f & 7) << 2;
            f32x4 v = *(const f32x4*)&db[a * 256 + ec * 32 + e4];
            h4v h; h[0]=(_Float16)v[0]; h[1]=(_Float16)v[1]; h[2]=(_Float16)v[2]; h[3]=(_Float16)v[3];
            *(h4v*)&rB[a * 40 + e4] = h;
        }
        __syncthreads();
        #pragma unroll
        for (int j = 0; j < 32; j += 8) {
            h8 hv = *(const h8*)&rB[tid * 40 + j];
            #pragma unroll
            for (int u = 0; u < 8; ++u) vd_r += (float)hv[u] * Vd[ec * 32 + j + u];
        }
        h8 af[4], bf[4];
        #pragma unroll
        for (int mt = 0; mt < 4; ++mt)
            af[mt] = *(const h8*)&rA[(mt * 16 + l15) * QSTR + ec * 32 + quad * 8];
        #pragma unroll
        for (int nt = 0; nt < 4; ++nt)
            bf[nt] = *(const h8*)&rB[(wv * 64 + nt * 16 + l15) * 40 + quad * 8];
        #pragma unroll
        for (int mt = 0; mt < 4; ++mt)
            #pragma unroll
            for (int nt = 0; nt < 4; ++nt)
                acc[mt][nt] = __builtin_amdgcn_mfma_f32_16x16x32_f16(af[mt], bf[nt], acc[mt][nt], 0, 0, 0);
        __syncthreads();
    }
    {
        float* fB = (float*)rB;
        if (tid < 64) fB[tid] = vq_r;
        fB[64 + tid] = vd_r;
    }
    __syncthreads();
    {
        const float* vql = (const float*)rB;
        const float* vdl = vql + 64;
        float* ob = og + ((bb * 16 + kk) * 256 + qt * 64) * 256;
        #pragma unroll
        for (int mt = 0; mt < 4; ++mt)
            #pragma unroll
            for (int nt = 0; nt < 4; ++nt) {
                int a = wv * 64 + nt * 16 + l15;
                float va = vdl[a];
                #pragma unroll
                for (int reg = 0; reg < 4; ++reg) {
                    int q = mt * 16 + quad * 4 + reg;
                    float x = acc[mt][nt][reg] + vql[q] + va + bk;
                    ob[q * 256 + a] = 1.0f / (1.0f + __expf(-x));
                }
            }
    }
}

extern "C" void kernel_launch(void* const* d_in, const int* in_sizes, int n_in,
                              void* d_out, int out_size, void* d_ws, size_t ws_size,
                              hipStream_t stream) {
    (void)in_sizes; (void)n_in; (void)out_size;
    const float* qg = (const float*)d_in[0];
    const float* dg = (const float*)d_in[1];
    const float* wg = (const float*)d_in[2];
    const float* Vg = (const float*)d_in[3];
    const float* bg = (const float*)d_in[4];
    float* og = (float*)d_out;

    if (ws_size >= (size_t)WS_NEED) {
        char* ws = (char*)d_ws;
        _Float16* wsw = (_Float16*)(ws + WS_W_OFF);
        _Float16* qsp = (_Float16*)(ws + WS_Q_OFF);
        _Float16* dsp = (_Float16*)(ws + WS_D_OFF);
        float*    vqp = (float*)(ws + WS_VQ_OFF);
        float*    vdp = (float*)(ws + WS_VD_OFF);
        prep_q <<<512, 256, 0, stream>>>(qg, qsp);
        prep_da<<<512, 256, 0, stream>>>(dg, dsp);
        prep_w <<<128, 256, 0, stream>>>(wg, wsw);
        prep_v <<<512, 256, 0, stream>>>(qg, dg, Vg, vqp, vdp);
        ntn_hot<<<4096, 256, 0, stream>>>(qsp, dsp, wsw, vqp, vdp, bg, og);
    } else {
        ntn_fused_fb<<<4096, 256, 0, stream>>>(qg, dg, wg, Vg, bg, og);
    }
}